// Round 11
// baseline (561.492 us; speedup 1.0000x reference)
//
#include <hip/hip_runtime.h>
#include <hip/hip_bf16.h>

using bf16 = __hip_bfloat16;

#define NEG_SLOPE 0.01f

typedef float f32x4u __attribute__((ext_vector_type(4), aligned(4)));
typedef unsigned short u16x4u __attribute__((ext_vector_type(4), aligned(2)));

__device__ __forceinline__ float bf_lo(unsigned int v) { return __uint_as_float(v << 16); }
__device__ __forceinline__ float bf_hi(unsigned int v) { return __uint_as_float(v & 0xffff0000u); }
__device__ __forceinline__ float b2f(unsigned short u) { return __uint_as_float((unsigned int)u << 16); }
__device__ __forceinline__ float rdlane(float v, int lane) {
  return __uint_as_float(__builtin_amdgcn_readlane(__float_as_uint(v), lane));
}

// ---------------------------------------------------------------------------
// k_zero: one dispatch zeroing the contiguous {s1, s2, deg} region (3N words)
// ---------------------------------------------------------------------------
__global__ void k_zero(unsigned int* __restrict__ p, int n) {
  int i = blockIdx.x * 256 + threadIdx.x;
  if (i < n) p[i] = 0u;
}

// ---------------------------------------------------------------------------
// k_prep: fold e = r@rel_w.T + rel_b through the attention vectors + all
// scalar biases into per-layer constants.
//   consts[0..31]=v1, consts[32..63]=v2, consts[64]=c1, consts[65]=c2
// ---------------------------------------------------------------------------
__global__ void k_prep(const float* __restrict__ rel_w, const float* __restrict__ rel_b,
                       const float* __restrict__ ew1_w, const float* __restrict__ ew1_b,
                       const float* __restrict__ ew2_w, const float* __restrict__ ew2_b,
                       const float* __restrict__ ai1_b, const float* __restrict__ aj1_b,
                       const float* __restrict__ ai2_b, const float* __restrict__ aj2_b,
                       float* __restrict__ consts) {
  int t = threadIdx.x;
  if (t < 32) {
    float a1 = 0.f, a2 = 0.f;
    for (int o = 0; o < 64; ++o) {
      float w = rel_w[o * 32 + t];
      a1 += w * ew1_w[o];
      a2 += w * ew2_w[o];
    }
    consts[t] = a1;
    consts[32 + t] = a2;
  } else if (t == 32) {
    float c = 0.f;
    for (int o = 0; o < 64; ++o) c += rel_b[o] * ew1_w[o];
    consts[64] = c + ew1_b[0] + ai1_b[0] + aj1_b[0];
  } else if (t == 33) {
    float c = 0.f;
    for (int o = 0; o < 64; ++o) c += rel_b[o] * ew2_w[o];
    consts[65] = c + ew2_b[0] + ai2_b[0] + aj2_b[0];
  }
}

// ---------------------------------------------------------------------------
// k_deg: 4 edges per thread (vectorized read), atomic degree count.
// ---------------------------------------------------------------------------
__global__ void k_deg(const int* __restrict__ dst, int* __restrict__ deg, int E) {
  int e4 = (blockIdx.x * 256 + threadIdx.x) * 4;
  if (e4 + 3 < E) {
    int4 d = *(const int4*)(dst + e4);
    atomicAdd(&deg[d.x], 1);
    atomicAdd(&deg[d.y], 1);
    atomicAdd(&deg[d.z], 1);
    atomicAdd(&deg[d.w], 1);
  } else {
    for (int e = e4; e < E; ++e) atomicAdd(&deg[dst[e]], 1);
  }
}

// ---------------------------------------------------------------------------
// 3-phase parallel exclusive scan (N ~ 50k, NB <= 256)
// ---------------------------------------------------------------------------
__global__ __launch_bounds__(256) void k_scan_sum(const int* __restrict__ deg,
                                                  int* __restrict__ bsum, int N) {
  __shared__ int ws_[4];
  int t = threadIdx.x;
  int i = blockIdx.x * 256 + t;
  int v = (i < N) ? deg[i] : 0;
  #pragma unroll
  for (int m = 32; m >= 1; m >>= 1) v += __shfl_xor(v, m, 64);
  if ((t & 63) == 0) ws_[t >> 6] = v;
  __syncthreads();
  if (t == 0) bsum[blockIdx.x] = ws_[0] + ws_[1] + ws_[2] + ws_[3];
}

__global__ __launch_bounds__(256) void k_scan_bsum(const int* __restrict__ bsum,
                                                   int* __restrict__ bsumx,
                                                   int* __restrict__ off,
                                                   int NB, int N, int E) {
  __shared__ int part[256];
  int t = threadIdx.x;
  part[t] = (t < NB) ? bsum[t] : 0;
  __syncthreads();
  for (int d = 1; d < 256; d <<= 1) {
    int v = (t >= d) ? part[t - d] : 0;
    __syncthreads();
    part[t] += v;
    __syncthreads();
  }
  if (t < NB) bsumx[t] = (t == 0) ? 0 : part[t - 1];
  if (t == 0) off[N] = E;
}

__global__ __launch_bounds__(256) void k_scan_out(const int* __restrict__ deg,
                                                  const int* __restrict__ bsumx,
                                                  int* __restrict__ off,
                                                  int* __restrict__ pos, int N) {
  __shared__ int wsum[4];
  int t = threadIdx.x;
  int lane = t & 63;
  int wave = t >> 6;
  int i = blockIdx.x * 256 + t;
  int v = (i < N) ? deg[i] : 0;
  int incl = v;
  #pragma unroll
  for (int d = 1; d < 64; d <<= 1) {
    int u = __shfl_up(incl, d, 64);
    if (lane >= d) incl += u;
  }
  int wtot = __shfl(incl, 63, 64);
  if (lane == 0) wsum[wave] = wtot;
  __syncthreads();
  int woff = 0;
  for (int w = 0; w < 4; ++w) woff += (w < wave) ? wsum[w] : 0;
  if (i < N) {
    int o = bsumx[blockIdx.x] + woff + (incl - v);
    off[i] = o;
    pos[i] = o;
  }
}

// ---------------------------------------------------------------------------
// k_fill: XCD-PARTITIONED scatter. Block b owns dst-partition q = b&7
// (matches XCD under round-robin dispatch; a mapping change only affects
// speed). All writers of a given ed line share one L2 -> full-line
// writebacks once (R6: WRITE 52MB partial-sector -> clean).
//   ed[p] = eid<<32 | dst<<16 | src
// ---------------------------------------------------------------------------
__global__ void k_fill(const int* __restrict__ src, const int* __restrict__ dst,
                       int* __restrict__ pos, unsigned long long* __restrict__ ed,
                       int E, int pw, int N) {
  int q = blockIdx.x & 7;           // partition id (round-robin -> same XCD)
  int chunk = blockIdx.x >> 3;
  int lo = q * pw;
  int hi = lo + pw; if (hi > N) hi = N;
  int e4 = (chunk * 256 + threadIdx.x) * 4;
  if (e4 + 3 < E) {
    int4 d4 = *(const int4*)(dst + e4);
    bool m0 = (d4.x >= lo) & (d4.x < hi);
    bool m1 = (d4.y >= lo) & (d4.y < hi);
    bool m2 = (d4.z >= lo) & (d4.z < hi);
    bool m3 = (d4.w >= lo) & (d4.w < hi);
    if (m0 | m1 | m2 | m3) {
      int4 s4 = *(const int4*)(src + e4);
      if (m0) {
        int p = atomicAdd(&pos[d4.x], 1);
        ed[p] = ((unsigned long long)(unsigned)e4 << 32) |
                ((unsigned)d4.x << 16) | (unsigned)s4.x;
      }
      if (m1) {
        int p = atomicAdd(&pos[d4.y], 1);
        ed[p] = ((unsigned long long)(unsigned)(e4 + 1) << 32) |
                ((unsigned)d4.y << 16) | (unsigned)s4.y;
      }
      if (m2) {
        int p = atomicAdd(&pos[d4.z], 1);
        ed[p] = ((unsigned long long)(unsigned)(e4 + 2) << 32) |
                ((unsigned)d4.z << 16) | (unsigned)s4.z;
      }
      if (m3) {
        int p = atomicAdd(&pos[d4.w], 1);
        ed[p] = ((unsigned long long)(unsigned)(e4 + 3) << 32) |
                ((unsigned)d4.w << 16) | (unsigned)s4.w;
      }
    }
  } else {
    for (int e = e4; e < E; ++e) {
      int d = dst[e];
      if (d >= lo && d < hi) {
        int p = atomicAdd(&pos[d], 1);
        ed[p] = ((unsigned long long)(unsigned)e << 32) |
                ((unsigned)d << 16) | (unsigned)src[e];
      }
    }
  }
}

// ---------------------------------------------------------------------------
// k_perm: p-order; gathers the BIG payload. Each r row is 128B aligned =
// exactly one cacheline -> random FULL-LINE reads, zero fetch amplification.
// All writes (r_s, ewd1, ewd2, src_s, dst_s) are p-order sequential -> zero
// write amplification. 8 independent row gathers in flight per 32-lane group.
// ---------------------------------------------------------------------------
__global__ __launch_bounds__(256) void k_perm(const unsigned long long* __restrict__ ed,
                                              const float* __restrict__ r,
                                              const float* __restrict__ consts,
                                              float* __restrict__ ewd1_s,
                                              float* __restrict__ ewd2_s,
                                              unsigned short* __restrict__ src_s,
                                              unsigned short* __restrict__ dst_s,
                                              bf16* __restrict__ r_s, int E) {
  int t = threadIdx.x;
  int k = t & 31;
  int g = blockIdx.x * 8 + (t >> 5);
  int p0 = g * 8;
  if (p0 >= E) return;
  float v1k = consts[k], v2k = consts[32 + k];
  float c1 = consts[64], c2 = consts[65];
  if (p0 + 8 <= E) {
    unsigned long long v0 = ed[p0],     v1 = ed[p0 + 1], v2 = ed[p0 + 2], v3 = ed[p0 + 3];
    unsigned long long v4 = ed[p0 + 4], v5 = ed[p0 + 5], v6 = ed[p0 + 6], v7 = ed[p0 + 7];
    int e0 = (int)(v0 >> 32), e1 = (int)(v1 >> 32), e2 = (int)(v2 >> 32), e3 = (int)(v3 >> 32);
    int e4 = (int)(v4 >> 32), e5 = (int)(v5 >> 32), e6 = (int)(v6 >> 32), e7 = (int)(v7 >> 32);
    // 8 independent 128B random full-line reads in flight
    float r0 = r[(size_t)e0 * 32 + k];
    float r1 = r[(size_t)e1 * 32 + k];
    float r2 = r[(size_t)e2 * 32 + k];
    float r3 = r[(size_t)e3 * 32 + k];
    float r4 = r[(size_t)e4 * 32 + k];
    float r5 = r[(size_t)e5 * 32 + k];
    float r6 = r[(size_t)e6 * 32 + k];
    float r7 = r[(size_t)e7 * 32 + k];
    // sequential bf16 writes: 512B contiguous per group
    bf16* wp = r_s + (size_t)p0 * 32 + k;
    wp[0]   = __float2bfloat16(r0);
    wp[32]  = __float2bfloat16(r1);
    wp[64]  = __float2bfloat16(r2);
    wp[96]  = __float2bfloat16(r3);
    wp[128] = __float2bfloat16(r4);
    wp[160] = __float2bfloat16(r5);
    wp[192] = __float2bfloat16(r6);
    wp[224] = __float2bfloat16(r7);
    float a0 = r0 * v1k, b0 = r0 * v2k;
    float a1 = r1 * v1k, b1 = r1 * v2k;
    float a2 = r2 * v1k, b2 = r2 * v2k;
    float a3 = r3 * v1k, b3 = r3 * v2k;
    float a4 = r4 * v1k, b4 = r4 * v2k;
    float a5 = r5 * v1k, b5 = r5 * v2k;
    float a6 = r6 * v1k, b6 = r6 * v2k;
    float a7 = r7 * v1k, b7 = r7 * v2k;
    #pragma unroll
    for (int m = 16; m >= 1; m >>= 1) {
      a0 += __shfl_xor(a0, m, 64);  b0 += __shfl_xor(b0, m, 64);
      a1 += __shfl_xor(a1, m, 64);  b1 += __shfl_xor(b1, m, 64);
      a2 += __shfl_xor(a2, m, 64);  b2 += __shfl_xor(b2, m, 64);
      a3 += __shfl_xor(a3, m, 64);  b3 += __shfl_xor(b3, m, 64);
      a4 += __shfl_xor(a4, m, 64);  b4 += __shfl_xor(b4, m, 64);
      a5 += __shfl_xor(a5, m, 64);  b5 += __shfl_xor(b5, m, 64);
      a6 += __shfl_xor(a6, m, 64);  b6 += __shfl_xor(b6, m, 64);
      a7 += __shfl_xor(a7, m, 64);  b7 += __shfl_xor(b7, m, 64);
    }
    if (k == 0) {
      ewd1_s[p0]     = a0 + c1;  ewd2_s[p0]     = b0 + c2;
      ewd1_s[p0 + 1] = a1 + c1;  ewd2_s[p0 + 1] = b1 + c2;
      ewd1_s[p0 + 2] = a2 + c1;  ewd2_s[p0 + 2] = b2 + c2;
      ewd1_s[p0 + 3] = a3 + c1;  ewd2_s[p0 + 3] = b3 + c2;
      ewd1_s[p0 + 4] = a4 + c1;  ewd2_s[p0 + 4] = b4 + c2;
      ewd1_s[p0 + 5] = a5 + c1;  ewd2_s[p0 + 5] = b5 + c2;
      ewd1_s[p0 + 6] = a6 + c1;  ewd2_s[p0 + 6] = b6 + c2;
      ewd1_s[p0 + 7] = a7 + c1;  ewd2_s[p0 + 7] = b7 + c2;
      ushort4 sl, sh, dl, dh;
      sl.x = (unsigned short)(v0 & 0xFFFF); sl.y = (unsigned short)(v1 & 0xFFFF);
      sl.z = (unsigned short)(v2 & 0xFFFF); sl.w = (unsigned short)(v3 & 0xFFFF);
      sh.x = (unsigned short)(v4 & 0xFFFF); sh.y = (unsigned short)(v5 & 0xFFFF);
      sh.z = (unsigned short)(v6 & 0xFFFF); sh.w = (unsigned short)(v7 & 0xFFFF);
      dl.x = (unsigned short)((v0 >> 16) & 0xFFFF); dl.y = (unsigned short)((v1 >> 16) & 0xFFFF);
      dl.z = (unsigned short)((v2 >> 16) & 0xFFFF); dl.w = (unsigned short)((v3 >> 16) & 0xFFFF);
      dh.x = (unsigned short)((v4 >> 16) & 0xFFFF); dh.y = (unsigned short)((v5 >> 16) & 0xFFFF);
      dh.z = (unsigned short)((v6 >> 16) & 0xFFFF); dh.w = (unsigned short)((v7 >> 16) & 0xFFFF);
      *(ushort4*)(src_s + p0)     = sl;
      *(ushort4*)(src_s + p0 + 4) = sh;
      *(ushort4*)(dst_s + p0)     = dl;
      *(ushort4*)(dst_s + p0 + 4) = dh;
    }
  } else {
    for (int p = p0; p < E; ++p) {
      unsigned long long v = ed[p];
      int e = (int)(v >> 32);
      float rv = r[(size_t)e * 32 + k];
      r_s[(size_t)p * 32 + k] = __float2bfloat16(rv);
      float a = rv * v1k, b = rv * v2k;
      #pragma unroll
      for (int m = 16; m >= 1; m >>= 1) {
        a += __shfl_xor(a, m, 64);
        b += __shfl_xor(b, m, 64);
      }
      if (k == 0) {
        ewd1_s[p] = a + c1; ewd2_s[p] = b + c2;
        src_s[p] = (unsigned short)(v & 0xFFFF);
        dst_s[p] = (unsigned short)((v >> 16) & 0xFFFF);
      }
    }
  }
}

// ---------------------------------------------------------------------------
// k_x: x[n] = in[n] @ W.T + b (bf16 out), plus aid/ajd per-node scalars.
// ZERO LDS ops in the inner product. Lane l holds W row l in 64 VGPRs
// (static-indexed); the in-row is read via wave-UNIFORM scalar loads.
// ---------------------------------------------------------------------------
__global__ __launch_bounds__(256) void k_x(const float* __restrict__ in,
                                           const float* __restrict__ W,
                                           const float* __restrict__ b,
                                           const float* __restrict__ ai_w,
                                           const float* __restrict__ aj_w,
                                           bf16* __restrict__ x,
                                           float* __restrict__ aid,
                                           float* __restrict__ ajd, int N) {
  int t = threadIdx.x;
  int l = t & 63;
  // per-lane weight row: w[c] = W[l][c] (64 VGPRs, static indexing only)
  float w[64];
  #pragma unroll
  for (int c4 = 0; c4 < 16; ++c4) {
    float4 v = *(const float4*)(W + l * 64 + c4 * 4);
    w[c4 * 4]     = v.x;
    w[c4 * 4 + 1] = v.y;
    w[c4 * 4 + 2] = v.z;
    w[c4 * 4 + 3] = v.w;
  }
  float aw = ai_w[l], jw = aj_w[l], bl = b[l];
  int wid = __builtin_amdgcn_readfirstlane(t >> 6);  // provably wave-uniform
  int nwaves = gridDim.x * 4;
  for (int n = blockIdx.x * 4 + wid; n < N; n += nwaves) {
    const float* rowp = in + (size_t)n * 64;  // uniform address -> s_load
    float a0 = 0.f, a1 = 0.f, a2 = 0.f, a3 = 0.f;
    #pragma unroll
    for (int c = 0; c < 64; c += 4) {
      a0 = fmaf(rowp[c],     w[c],     a0);
      a1 = fmaf(rowp[c + 1], w[c + 1], a1);
      a2 = fmaf(rowp[c + 2], w[c + 2], a2);
      a3 = fmaf(rowp[c + 3], w[c + 3], a3);
    }
    float acc = bl + ((a0 + a1) + (a2 + a3));
    x[(size_t)n * 64 + l] = __float2bfloat16(acc);
    float pa = acc * aw, pj = acc * jw;
    #pragma unroll
    for (int m = 32; m >= 1; m >>= 1) {
      pa += __shfl_xor(pa, m, 64);
      pj += __shfl_xor(pj, m, 64);
    }
    if (l == 0) { aid[n] = pa; ajd[n] = pj; }
  }
}

// ---------------------------------------------------------------------------
// k_alpha: p-order, 4 edges/thread vectorized (ushort4/float4), 4 independent
// aid/ajd table gathers in flight.
//   ex[p] = exp(leaky_relu(aid[dst]+ajd[src]+ewd[p]));  s[src] += ex
// ---------------------------------------------------------------------------
__global__ void k_alpha(const unsigned short* __restrict__ src_s,
                        const unsigned short* __restrict__ dst_s,
                        const float* __restrict__ aid, const float* __restrict__ ajd,
                        const float* __restrict__ ewd,
                        float* __restrict__ ex, float* __restrict__ s, int E) {
  int p4 = (blockIdx.x * 256 + threadIdx.x) * 4;
  if (p4 + 4 <= E) {
    ushort4 sv = *(const ushort4*)(src_s + p4);
    ushort4 dv = *(const ushort4*)(dst_s + p4);
    float4 ew = *(const float4*)(ewd + p4);
    float a0 = aid[dv.x] + ajd[sv.x] + ew.x;
    float a1 = aid[dv.y] + ajd[sv.y] + ew.y;
    float a2 = aid[dv.z] + ajd[sv.z] + ew.z;
    float a3 = aid[dv.w] + ajd[sv.w] + ew.w;
    a0 = (a0 > 0.f) ? a0 : a0 * NEG_SLOPE;
    a1 = (a1 > 0.f) ? a1 : a1 * NEG_SLOPE;
    a2 = (a2 > 0.f) ? a2 : a2 * NEG_SLOPE;
    a3 = (a3 > 0.f) ? a3 : a3 * NEG_SLOPE;
    float e0 = __expf(a0), e1 = __expf(a1), e2 = __expf(a2), e3 = __expf(a3);
    *(float4*)(ex + p4) = make_float4(e0, e1, e2, e3);
    atomicAdd(&s[sv.x], e0);
    atomicAdd(&s[sv.y], e1);
    atomicAdd(&s[sv.z], e2);
    atomicAdd(&s[sv.w], e3);
  } else if (p4 < E) {
    for (int p = p4; p < E; ++p) {
      int sn = src_s[p];
      float a = aid[dst_s[p]] + ajd[sn] + ewd[p];
      a = (a > 0.f) ? a : a * NEG_SLOPE;
      float ev = __expf(a);
      ex[p] = ev;
      atomicAdd(&s[sn], ev);
    }
  }
}

// ---------------------------------------------------------------------------
// k_wnorm: w[p] = ex[p] * rcp(s[src[p]] + eps), edge-parallel & vectorized.
// Moves the (lane-invariant, redundantly-recomputed) softmax normalization
// out of k_agg's half-wave loop: each w computed ONCE per edge instead of
// 32x per half-wave, and the ex->s-gather->mul dependent chain leaves
// k_agg's critical path entirely.
// ---------------------------------------------------------------------------
__global__ void k_wnorm(const unsigned short* __restrict__ src_s,
                        const float* __restrict__ ex, const float* __restrict__ s,
                        float* __restrict__ w, int E) {
  int p4 = (blockIdx.x * 256 + threadIdx.x) * 4;
  if (p4 + 4 <= E) {
    ushort4 sv = *(const ushort4*)(src_s + p4);
    float4 e4 = *(const float4*)(ex + p4);
    float4 wv;
    wv.x = e4.x * __builtin_amdgcn_rcpf(s[sv.x] + 1e-16f);
    wv.y = e4.y * __builtin_amdgcn_rcpf(s[sv.y] + 1e-16f);
    wv.z = e4.z * __builtin_amdgcn_rcpf(s[sv.z] + 1e-16f);
    wv.w = e4.w * __builtin_amdgcn_rcpf(s[sv.w] + 1e-16f);
    *(float4*)(w + p4) = wv;
  } else if (p4 < E) {
    for (int p = p4; p < E; ++p)
      w[p] = ex[p] * __builtin_amdgcn_rcpf(s[src_s[p]] + 1e-16f);
  }
}

// ---------------------------------------------------------------------------
// k_agg: atomic-free aggregation over CSR-by-dst, half-wave edge split.
// R9: consumes precomputed w[] (k_wnorm). Halves now take CONTIGUOUS 4-edge
// blocks (half0: [b,b+4), half1: [b+4,b+8)) so w loads as one dwordx4 and
// src_s as one packed vector (4B/2B-aligned ext-vectors; gfx9 multi-dword
// loads need only dword alignment). Main-loop VMEM per 8-edge iter per
// half: 20 -> 10; rcp and s-gather leave the loop.
// ---------------------------------------------------------------------------
__global__ __launch_bounds__(256, 8) void k_agg(const int* __restrict__ off,
                                             const unsigned short* __restrict__ src_s,
                                             const float* __restrict__ w,
                                             const bf16* __restrict__ x,
                                             const bf16* __restrict__ r_s,
                                             const float* __restrict__ rel_w,
                                             const float* __restrict__ rel_b,
                                             float* __restrict__ out, int N) {
  __shared__ float RT[32 * 64];  // RT[k][o] = rel_w[o][k]
  int t = threadIdx.x;
  for (int idx = t; idx < 2048; idx += 256) {
    int o = idx >> 5, kk = idx & 31;
    RT[kk * 64 + o] = rel_w[idx];
  }
  __syncthreads();
  int l = t & 63;
  int k = l & 31;        // lane within half; owns channels 2k, 2k+1
  int half = l >> 5;     // 0 or 1
  int wave = t >> 6;
  int nwaves = gridDim.x * 4;
  const unsigned short* xu = (const unsigned short*)x;
  const unsigned short* ru = (const unsigned short*)r_s;
  float2 rbl = *(const float2*)(rel_b + 2 * k);
  for (int n = blockIdx.x * 4 + wave; n < N; n += nwaves) {
    int p0 = off[n], p1 = off[n + 1];
    float ax0 = 0.f, ax1 = 0.f, aq = 0.f, ws = 0.f;
    int b = p0;
    for (; b + 8 <= p1; b += 8) {
      int q0 = b + half * 4;  // contiguous 4-edge block per half
      u16x4u sv = *(const u16x4u*)(src_s + q0);
      f32x4u wv = *(const f32x4u*)(w + q0);
      int s0 = sv.x, s1 = sv.y, s2 = sv.z, s3 = sv.w;
      // 8 independent 128B row gathers in flight per wave (4 per half)
      unsigned int xv0 = *(const unsigned int*)(xu + ((size_t)s0 << 6) + 2 * k);
      unsigned int xv1 = *(const unsigned int*)(xu + ((size_t)s1 << 6) + 2 * k);
      unsigned int xv2 = *(const unsigned int*)(xu + ((size_t)s2 << 6) + 2 * k);
      unsigned int xv3 = *(const unsigned int*)(xu + ((size_t)s3 << 6) + 2 * k);
      float rv0 = b2f(ru[(size_t)q0 * 32 + k]);
      float rv1 = b2f(ru[(size_t)(q0 + 1) * 32 + k]);
      float rv2 = b2f(ru[(size_t)(q0 + 2) * 32 + k]);
      float rv3 = b2f(ru[(size_t)(q0 + 3) * 32 + k]);
      ax0 += wv.x * bf_lo(xv0) + wv.y * bf_lo(xv1) + wv.z * bf_lo(xv2) + wv.w * bf_lo(xv3);
      ax1 += wv.x * bf_hi(xv0) + wv.y * bf_hi(xv1) + wv.z * bf_hi(xv2) + wv.w * bf_hi(xv3);
      aq  += wv.x * rv0 + wv.y * rv1 + wv.z * rv2 + wv.w * rv3;
      ws  += wv.x + wv.y + wv.z + wv.w;
    }
    for (; b + 2 <= p1; b += 2) {
      int q = b + half;
      int sn = src_s[q];
      float wq = w[q];
      unsigned int xv = *(const unsigned int*)(xu + ((size_t)sn << 6) + 2 * k);
      ax0 += wq * bf_lo(xv);
      ax1 += wq * bf_hi(xv);
      aq  += wq * b2f(ru[(size_t)q * 32 + k]);
      ws  += wq;
    }
    if (b < p1 && half == 0) {  // single leftover edge -> half 0
      int sn = src_s[b];
      float wq = w[b];
      unsigned int xv = *(const unsigned int*)(xu + ((size_t)sn << 6) + 2 * k);
      ax0 += wq * bf_lo(xv);
      ax1 += wq * bf_hi(xv);
      aq  += wq * b2f(ru[(size_t)b * 32 + k]);
      ws  += wq;
    }
    // merge the two halves (aq/ws/ax* identical in both halves afterwards)
    ax0 += __shfl_xor(ax0, 32, 64);
    ax1 += __shfl_xor(ax1, 32, 64);
    aq  += __shfl_xor(aq, 32, 64);
    ws  += __shfl_xor(ws, 32, 64);
    float a0 = ax0 + ws * rbl.x;
    float a1 = ax1 + ws * rbl.y;
    #pragma unroll
    for (int kk = 0; kk < 32; ++kk) {
      float qk = rdlane(aq, kk);  // constant-lane broadcast: no LDS traffic
      float2 rt = *(const float2*)(RT + kk * 64 + 2 * k);
      a0 += qk * rt.x;
      a1 += qk * rt.y;
    }
    if (half == 0) {
      *(float2*)(out + ((size_t)n << 6) + 2 * k) =
          make_float2(fmaxf(a0, 0.f), fmaxf(a1, 0.f));
    }
  }
}

// ---------------------------------------------------------------------------
extern "C" void kernel_launch(void* const* d_in, const int* in_sizes, int n_in,
                              void* d_out, int out_size, void* d_ws, size_t ws_size,
                              hipStream_t stream) {
  const float* feat   = (const float*)d_in[0];
  const int*   eidx   = (const int*)d_in[1];
  const float* r      = (const float*)d_in[2];
  const float* rel_w  = (const float*)d_in[3];
  const float* rel_b  = (const float*)d_in[4];
  const float* c1_lw  = (const float*)d_in[5];
  const float* c1_lb  = (const float*)d_in[6];
  const float* c1_aiw = (const float*)d_in[7];
  const float* c1_aib = (const float*)d_in[8];
  const float* c1_ajw = (const float*)d_in[9];
  const float* c1_ajb = (const float*)d_in[10];
  const float* c1_eww = (const float*)d_in[11];
  const float* c1_ewb = (const float*)d_in[12];
  const float* c2_lw  = (const float*)d_in[13];
  const float* c2_lb  = (const float*)d_in[14];
  const float* c2_aiw = (const float*)d_in[15];
  const float* c2_aib = (const float*)d_in[16];
  const float* c2_ajw = (const float*)d_in[17];
  const float* c2_ajb = (const float*)d_in[18];
  const float* c2_eww = (const float*)d_in[19];
  const float* c2_ewb = (const float*)d_in[20];
  float* out = (float*)d_out;

  const int N = in_sizes[0] / 64;
  const int E = in_sizes[1] / 2;
  const int* src = eidx;
  const int* dst = eidx + E;

  // ---- workspace carve (~91 MB) ----
  // s1, s2, deg are contiguous so one k_zero covers all three.
  float* wsf    = (float*)d_ws;
  float* consts = wsf;                          // 128
  float* ewd1_s = wsf + 128;                    // E (p-order)
  float* ewd2_s = ewd1_s + E;                   // E
  float* ex     = ewd2_s + E;                   // E
  float* s1     = ex + E;                       // N (zero region begin)
  float* s2     = s1 + N;                       // N
  int*   deg    = (int*)(s2 + N);               // N (zero region end)
  float* aid    = (float*)(deg + N);            // N
  float* ajd    = aid + N;                      // N
  float* h1     = ajd + N;                      // N*64 f32 (inter-layer, seq)
  bf16*  x      = (bf16*)(h1 + (size_t)N * 64); // N*64 bf16 (gathered table)
  int*   off    = (int*)(x + (size_t)N * 64);   // N+1
  int*   pos    = off + N + 1;                  // N
  int*   bsum   = pos + N;                      // 256
  int*   bsumx  = bsum + 256;                   // 256
  // 16B-align ed (u64 packed edge records)
  size_t ofs = (size_t)((char*)(bsumx + 256) - (char*)d_ws);
  ofs = (ofs + 15) & ~(size_t)15;
  unsigned long long* ed = (unsigned long long*)((char*)d_ws + ofs);  // E u64
  unsigned short* src_s = (unsigned short*)(ed + E);                  // E u16
  unsigned short* dst_s = src_s + E;                                  // E u16
  bf16* r_s = (bf16*)(dst_s + E);                                     // E*32 bf16
  // w aliases ed: ed is dead after k_perm (prep phase); w (E f32 = 3.2MB)
  // fits in ed's 6.4MB footprint -> zero extra workspace.
  float* w = (float*)ed;

  const int blocksE4  = (E + 1023) / 1024;   // 4 edges/thread kernels
  const int blocksF   = 8 * blocksE4;        // k_fill: 8 partitions x chunks
  const int blocksP8  = (E + 63) / 64;       // k_perm: 8 groups x 8 rows/block
  const int blocksN   = (N + 255) / 256;
  const int blocksN3  = (3 * N + 255) / 256; // fused zero of s1,s2,deg
  const int gridP     = 2048;
  const int pw        = (N + 7) / 8;         // dst-partition width

  // ---- shared prep (both layers) ----
  k_zero<<<blocksN3, 256, 0, stream>>>((unsigned int*)s1, 3 * N);
  k_prep<<<1, 64, 0, stream>>>(rel_w, rel_b, c1_eww, c1_ewb, c2_eww, c2_ewb,
                               c1_aib, c1_ajb, c2_aib, c2_ajb, consts);
  k_deg<<<blocksE4, 256, 0, stream>>>(dst, deg, E);
  k_scan_sum<<<blocksN, 256, 0, stream>>>(deg, bsum, N);
  k_scan_bsum<<<1, 256, 0, stream>>>(bsum, bsumx, off, blocksN, N, E);
  k_scan_out<<<blocksN, 256, 0, stream>>>(deg, bsumx, off, pos, N);
  k_fill<<<blocksF, 256, 0, stream>>>(src, dst, pos, ed, E, pw, N);
  k_perm<<<blocksP8, 256, 0, stream>>>(ed, r, consts, ewd1_s, ewd2_s,
                                       src_s, dst_s, r_s, E);

  // ---- layer 1 ----
  k_x<<<gridP, 256, 0, stream>>>(feat, c1_lw, c1_lb, c1_aiw, c1_ajw, x, aid, ajd, N);
  k_alpha<<<blocksE4, 256, 0, stream>>>(src_s, dst_s, aid, ajd, ewd1_s, ex, s1, E);
  k_wnorm<<<blocksE4, 256, 0, stream>>>(src_s, ex, s1, w, E);
  k_agg<<<gridP, 256, 0, stream>>>(off, src_s, w, x, r_s, rel_w, rel_b, h1, N);

  // ---- layer 2 ----
  k_x<<<gridP, 256, 0, stream>>>(h1, c2_lw, c2_lb, c2_aiw, c2_ajw, x, aid, ajd, N);
  k_alpha<<<blocksE4, 256, 0, stream>>>(src_s, dst_s, aid, ajd, ewd2_s, ex, s2, E);
  k_wnorm<<<blocksE4, 256, 0, stream>>>(src_s, ex, s2, w, E);
  k_agg<<<gridP, 256, 0, stream>>>(off, src_s, w, x, r_s, rel_w, rel_b, out, N);
}

// Round 12
// 549.709 us; speedup vs baseline: 1.0214x; 1.0214x over previous
//
#include <hip/hip_runtime.h>
#include <hip/hip_bf16.h>

using bf16 = __hip_bfloat16;

#define NEG_SLOPE 0.01f

__device__ __forceinline__ float bf_lo(unsigned int v) { return __uint_as_float(v << 16); }
__device__ __forceinline__ float bf_hi(unsigned int v) { return __uint_as_float(v & 0xffff0000u); }
__device__ __forceinline__ float b2f(unsigned short u) { return __uint_as_float((unsigned int)u << 16); }
__device__ __forceinline__ float rdlane(float v, int lane) {
  return __uint_as_float(__builtin_amdgcn_readlane(__float_as_uint(v), lane));
}

// ---------------------------------------------------------------------------
// k_zero: one dispatch zeroing the contiguous {s1, s2, deg} region (3N words)
// ---------------------------------------------------------------------------
__global__ void k_zero(unsigned int* __restrict__ p, int n) {
  int i = blockIdx.x * 256 + threadIdx.x;
  if (i < n) p[i] = 0u;
}

// ---------------------------------------------------------------------------
// k_prep: fold e = r@rel_w.T + rel_b through the attention vectors + all
// scalar biases into per-layer constants.
//   consts[0..31]=v1, consts[32..63]=v2, consts[64]=c1, consts[65]=c2
// ---------------------------------------------------------------------------
__global__ void k_prep(const float* __restrict__ rel_w, const float* __restrict__ rel_b,
                       const float* __restrict__ ew1_w, const float* __restrict__ ew1_b,
                       const float* __restrict__ ew2_w, const float* __restrict__ ew2_b,
                       const float* __restrict__ ai1_b, const float* __restrict__ aj1_b,
                       const float* __restrict__ ai2_b, const float* __restrict__ aj2_b,
                       float* __restrict__ consts) {
  int t = threadIdx.x;
  if (t < 32) {
    float a1 = 0.f, a2 = 0.f;
    for (int o = 0; o < 64; ++o) {
      float w = rel_w[o * 32 + t];
      a1 += w * ew1_w[o];
      a2 += w * ew2_w[o];
    }
    consts[t] = a1;
    consts[32 + t] = a2;
  } else if (t == 32) {
    float c = 0.f;
    for (int o = 0; o < 64; ++o) c += rel_b[o] * ew1_w[o];
    consts[64] = c + ew1_b[0] + ai1_b[0] + aj1_b[0];
  } else if (t == 33) {
    float c = 0.f;
    for (int o = 0; o < 64; ++o) c += rel_b[o] * ew2_w[o];
    consts[65] = c + ew2_b[0] + ai2_b[0] + aj2_b[0];
  }
}

// ---------------------------------------------------------------------------
// k_deg: 4 edges per thread (vectorized read), atomic degree count.
// ---------------------------------------------------------------------------
__global__ void k_deg(const int* __restrict__ dst, int* __restrict__ deg, int E) {
  int e4 = (blockIdx.x * 256 + threadIdx.x) * 4;
  if (e4 + 3 < E) {
    int4 d = *(const int4*)(dst + e4);
    atomicAdd(&deg[d.x], 1);
    atomicAdd(&deg[d.y], 1);
    atomicAdd(&deg[d.z], 1);
    atomicAdd(&deg[d.w], 1);
  } else {
    for (int e = e4; e < E; ++e) atomicAdd(&deg[dst[e]], 1);
  }
}

// ---------------------------------------------------------------------------
// 3-phase parallel exclusive scan (N ~ 50k, NB <= 256)
// ---------------------------------------------------------------------------
__global__ __launch_bounds__(256) void k_scan_sum(const int* __restrict__ deg,
                                                  int* __restrict__ bsum, int N) {
  __shared__ int ws_[4];
  int t = threadIdx.x;
  int i = blockIdx.x * 256 + t;
  int v = (i < N) ? deg[i] : 0;
  #pragma unroll
  for (int m = 32; m >= 1; m >>= 1) v += __shfl_xor(v, m, 64);
  if ((t & 63) == 0) ws_[t >> 6] = v;
  __syncthreads();
  if (t == 0) bsum[blockIdx.x] = ws_[0] + ws_[1] + ws_[2] + ws_[3];
}

__global__ __launch_bounds__(256) void k_scan_bsum(const int* __restrict__ bsum,
                                                   int* __restrict__ bsumx,
                                                   int* __restrict__ off,
                                                   int NB, int N, int E) {
  __shared__ int part[256];
  int t = threadIdx.x;
  part[t] = (t < NB) ? bsum[t] : 0;
  __syncthreads();
  for (int d = 1; d < 256; d <<= 1) {
    int v = (t >= d) ? part[t - d] : 0;
    __syncthreads();
    part[t] += v;
    __syncthreads();
  }
  if (t < NB) bsumx[t] = (t == 0) ? 0 : part[t - 1];
  if (t == 0) off[N] = E;
}

__global__ __launch_bounds__(256) void k_scan_out(const int* __restrict__ deg,
                                                  const int* __restrict__ bsumx,
                                                  int* __restrict__ off,
                                                  int* __restrict__ pos, int N) {
  __shared__ int wsum[4];
  int t = threadIdx.x;
  int lane = t & 63;
  int wave = t >> 6;
  int i = blockIdx.x * 256 + t;
  int v = (i < N) ? deg[i] : 0;
  int incl = v;
  #pragma unroll
  for (int d = 1; d < 64; d <<= 1) {
    int u = __shfl_up(incl, d, 64);
    if (lane >= d) incl += u;
  }
  int wtot = __shfl(incl, 63, 64);
  if (lane == 0) wsum[wave] = wtot;
  __syncthreads();
  int woff = 0;
  for (int w = 0; w < 4; ++w) woff += (w < wave) ? wsum[w] : 0;
  if (i < N) {
    int o = bsumx[blockIdx.x] + woff + (incl - v);
    off[i] = o;
    pos[i] = o;
  }
}

// ---------------------------------------------------------------------------
// k_fill: XCD-PARTITIONED scatter. Block b owns dst-partition q = b&7
// (matches XCD under round-robin dispatch; a mapping change only affects
// speed). All writers of a given ed line share one L2 -> full-line
// writebacks once (R6: WRITE 52MB partial-sector -> clean).
//   ed[p] = eid<<32 | dst<<16 | src
// ---------------------------------------------------------------------------
__global__ void k_fill(const int* __restrict__ src, const int* __restrict__ dst,
                       int* __restrict__ pos, unsigned long long* __restrict__ ed,
                       int E, int pw, int N) {
  int q = blockIdx.x & 7;           // partition id (round-robin -> same XCD)
  int chunk = blockIdx.x >> 3;
  int lo = q * pw;
  int hi = lo + pw; if (hi > N) hi = N;
  int e4 = (chunk * 256 + threadIdx.x) * 4;
  if (e4 + 3 < E) {
    int4 d4 = *(const int4*)(dst + e4);
    bool m0 = (d4.x >= lo) & (d4.x < hi);
    bool m1 = (d4.y >= lo) & (d4.y < hi);
    bool m2 = (d4.z >= lo) & (d4.z < hi);
    bool m3 = (d4.w >= lo) & (d4.w < hi);
    if (m0 | m1 | m2 | m3) {
      int4 s4 = *(const int4*)(src + e4);
      if (m0) {
        int p = atomicAdd(&pos[d4.x], 1);
        ed[p] = ((unsigned long long)(unsigned)e4 << 32) |
                ((unsigned)d4.x << 16) | (unsigned)s4.x;
      }
      if (m1) {
        int p = atomicAdd(&pos[d4.y], 1);
        ed[p] = ((unsigned long long)(unsigned)(e4 + 1) << 32) |
                ((unsigned)d4.y << 16) | (unsigned)s4.y;
      }
      if (m2) {
        int p = atomicAdd(&pos[d4.z], 1);
        ed[p] = ((unsigned long long)(unsigned)(e4 + 2) << 32) |
                ((unsigned)d4.z << 16) | (unsigned)s4.z;
      }
      if (m3) {
        int p = atomicAdd(&pos[d4.w], 1);
        ed[p] = ((unsigned long long)(unsigned)(e4 + 3) << 32) |
                ((unsigned)d4.w << 16) | (unsigned)s4.w;
      }
    }
  } else {
    for (int e = e4; e < E; ++e) {
      int d = dst[e];
      if (d >= lo && d < hi) {
        int p = atomicAdd(&pos[d], 1);
        ed[p] = ((unsigned long long)(unsigned)e << 32) |
                ((unsigned)d << 16) | (unsigned)src[e];
      }
    }
  }
}

// ---------------------------------------------------------------------------
// k_perm: p-order; gathers the BIG payload. Each r row is 128B aligned =
// exactly one cacheline -> random FULL-LINE reads, zero fetch amplification.
// All writes (r_s, ewd1, ewd2, src_s, dst_s) are p-order sequential -> zero
// write amplification. 8 independent row gathers in flight per 32-lane group.
// ---------------------------------------------------------------------------
__global__ __launch_bounds__(256) void k_perm(const unsigned long long* __restrict__ ed,
                                              const float* __restrict__ r,
                                              const float* __restrict__ consts,
                                              float* __restrict__ ewd1_s,
                                              float* __restrict__ ewd2_s,
                                              unsigned short* __restrict__ src_s,
                                              unsigned short* __restrict__ dst_s,
                                              bf16* __restrict__ r_s, int E) {
  int t = threadIdx.x;
  int k = t & 31;
  int g = blockIdx.x * 8 + (t >> 5);
  int p0 = g * 8;
  if (p0 >= E) return;
  float v1k = consts[k], v2k = consts[32 + k];
  float c1 = consts[64], c2 = consts[65];
  if (p0 + 8 <= E) {
    unsigned long long v0 = ed[p0],     v1 = ed[p0 + 1], v2 = ed[p0 + 2], v3 = ed[p0 + 3];
    unsigned long long v4 = ed[p0 + 4], v5 = ed[p0 + 5], v6 = ed[p0 + 6], v7 = ed[p0 + 7];
    int e0 = (int)(v0 >> 32), e1 = (int)(v1 >> 32), e2 = (int)(v2 >> 32), e3 = (int)(v3 >> 32);
    int e4 = (int)(v4 >> 32), e5 = (int)(v5 >> 32), e6 = (int)(v6 >> 32), e7 = (int)(v7 >> 32);
    // 8 independent 128B random full-line reads in flight
    float r0 = r[(size_t)e0 * 32 + k];
    float r1 = r[(size_t)e1 * 32 + k];
    float r2 = r[(size_t)e2 * 32 + k];
    float r3 = r[(size_t)e3 * 32 + k];
    float r4 = r[(size_t)e4 * 32 + k];
    float r5 = r[(size_t)e5 * 32 + k];
    float r6 = r[(size_t)e6 * 32 + k];
    float r7 = r[(size_t)e7 * 32 + k];
    // sequential bf16 writes: 512B contiguous per group
    bf16* wp = r_s + (size_t)p0 * 32 + k;
    wp[0]   = __float2bfloat16(r0);
    wp[32]  = __float2bfloat16(r1);
    wp[64]  = __float2bfloat16(r2);
    wp[96]  = __float2bfloat16(r3);
    wp[128] = __float2bfloat16(r4);
    wp[160] = __float2bfloat16(r5);
    wp[192] = __float2bfloat16(r6);
    wp[224] = __float2bfloat16(r7);
    float a0 = r0 * v1k, b0 = r0 * v2k;
    float a1 = r1 * v1k, b1 = r1 * v2k;
    float a2 = r2 * v1k, b2 = r2 * v2k;
    float a3 = r3 * v1k, b3 = r3 * v2k;
    float a4 = r4 * v1k, b4 = r4 * v2k;
    float a5 = r5 * v1k, b5 = r5 * v2k;
    float a6 = r6 * v1k, b6 = r6 * v2k;
    float a7 = r7 * v1k, b7 = r7 * v2k;
    #pragma unroll
    for (int m = 16; m >= 1; m >>= 1) {
      a0 += __shfl_xor(a0, m, 64);  b0 += __shfl_xor(b0, m, 64);
      a1 += __shfl_xor(a1, m, 64);  b1 += __shfl_xor(b1, m, 64);
      a2 += __shfl_xor(a2, m, 64);  b2 += __shfl_xor(b2, m, 64);
      a3 += __shfl_xor(a3, m, 64);  b3 += __shfl_xor(b3, m, 64);
      a4 += __shfl_xor(a4, m, 64);  b4 += __shfl_xor(b4, m, 64);
      a5 += __shfl_xor(a5, m, 64);  b5 += __shfl_xor(b5, m, 64);
      a6 += __shfl_xor(a6, m, 64);  b6 += __shfl_xor(b6, m, 64);
      a7 += __shfl_xor(a7, m, 64);  b7 += __shfl_xor(b7, m, 64);
    }
    if (k == 0) {
      ewd1_s[p0]     = a0 + c1;  ewd2_s[p0]     = b0 + c2;
      ewd1_s[p0 + 1] = a1 + c1;  ewd2_s[p0 + 1] = b1 + c2;
      ewd1_s[p0 + 2] = a2 + c1;  ewd2_s[p0 + 2] = b2 + c2;
      ewd1_s[p0 + 3] = a3 + c1;  ewd2_s[p0 + 3] = b3 + c2;
      ewd1_s[p0 + 4] = a4 + c1;  ewd2_s[p0 + 4] = b4 + c2;
      ewd1_s[p0 + 5] = a5 + c1;  ewd2_s[p0 + 5] = b5 + c2;
      ewd1_s[p0 + 6] = a6 + c1;  ewd2_s[p0 + 6] = b6 + c2;
      ewd1_s[p0 + 7] = a7 + c1;  ewd2_s[p0 + 7] = b7 + c2;
      ushort4 sl, sh, dl, dh;
      sl.x = (unsigned short)(v0 & 0xFFFF); sl.y = (unsigned short)(v1 & 0xFFFF);
      sl.z = (unsigned short)(v2 & 0xFFFF); sl.w = (unsigned short)(v3 & 0xFFFF);
      sh.x = (unsigned short)(v4 & 0xFFFF); sh.y = (unsigned short)(v5 & 0xFFFF);
      sh.z = (unsigned short)(v6 & 0xFFFF); sh.w = (unsigned short)(v7 & 0xFFFF);
      dl.x = (unsigned short)((v0 >> 16) & 0xFFFF); dl.y = (unsigned short)((v1 >> 16) & 0xFFFF);
      dl.z = (unsigned short)((v2 >> 16) & 0xFFFF); dl.w = (unsigned short)((v3 >> 16) & 0xFFFF);
      dh.x = (unsigned short)((v4 >> 16) & 0xFFFF); dh.y = (unsigned short)((v5 >> 16) & 0xFFFF);
      dh.z = (unsigned short)((v6 >> 16) & 0xFFFF); dh.w = (unsigned short)((v7 >> 16) & 0xFFFF);
      *(ushort4*)(src_s + p0)     = sl;
      *(ushort4*)(src_s + p0 + 4) = sh;
      *(ushort4*)(dst_s + p0)     = dl;
      *(ushort4*)(dst_s + p0 + 4) = dh;
    }
  } else {
    for (int p = p0; p < E; ++p) {
      unsigned long long v = ed[p];
      int e = (int)(v >> 32);
      float rv = r[(size_t)e * 32 + k];
      r_s[(size_t)p * 32 + k] = __float2bfloat16(rv);
      float a = rv * v1k, b = rv * v2k;
      #pragma unroll
      for (int m = 16; m >= 1; m >>= 1) {
        a += __shfl_xor(a, m, 64);
        b += __shfl_xor(b, m, 64);
      }
      if (k == 0) {
        ewd1_s[p] = a + c1; ewd2_s[p] = b + c2;
        src_s[p] = (unsigned short)(v & 0xFFFF);
        dst_s[p] = (unsigned short)((v >> 16) & 0xFFFF);
      }
    }
  }
}

// ---------------------------------------------------------------------------
// k_x: x[n] = in[n] @ W.T + b (bf16 out), plus aid/ajd per-node scalars.
// ZERO LDS ops in the inner product. Lane l holds W row l in 64 VGPRs
// (static-indexed); the in-row is read via wave-UNIFORM scalar loads.
// ---------------------------------------------------------------------------
__global__ __launch_bounds__(256) void k_x(const float* __restrict__ in,
                                           const float* __restrict__ W,
                                           const float* __restrict__ b,
                                           const float* __restrict__ ai_w,
                                           const float* __restrict__ aj_w,
                                           bf16* __restrict__ x,
                                           float* __restrict__ aid,
                                           float* __restrict__ ajd, int N) {
  int t = threadIdx.x;
  int l = t & 63;
  // per-lane weight row: w[c] = W[l][c] (64 VGPRs, static indexing only)
  float w[64];
  #pragma unroll
  for (int c4 = 0; c4 < 16; ++c4) {
    float4 v = *(const float4*)(W + l * 64 + c4 * 4);
    w[c4 * 4]     = v.x;
    w[c4 * 4 + 1] = v.y;
    w[c4 * 4 + 2] = v.z;
    w[c4 * 4 + 3] = v.w;
  }
  float aw = ai_w[l], jw = aj_w[l], bl = b[l];
  int wid = __builtin_amdgcn_readfirstlane(t >> 6);  // provably wave-uniform
  int nwaves = gridDim.x * 4;
  for (int n = blockIdx.x * 4 + wid; n < N; n += nwaves) {
    const float* rowp = in + (size_t)n * 64;  // uniform address -> s_load
    float a0 = 0.f, a1 = 0.f, a2 = 0.f, a3 = 0.f;
    #pragma unroll
    for (int c = 0; c < 64; c += 4) {
      a0 = fmaf(rowp[c],     w[c],     a0);
      a1 = fmaf(rowp[c + 1], w[c + 1], a1);
      a2 = fmaf(rowp[c + 2], w[c + 2], a2);
      a3 = fmaf(rowp[c + 3], w[c + 3], a3);
    }
    float acc = bl + ((a0 + a1) + (a2 + a3));
    x[(size_t)n * 64 + l] = __float2bfloat16(acc);
    float pa = acc * aw, pj = acc * jw;
    #pragma unroll
    for (int m = 32; m >= 1; m >>= 1) {
      pa += __shfl_xor(pa, m, 64);
      pj += __shfl_xor(pj, m, 64);
    }
    if (l == 0) { aid[n] = pa; ajd[n] = pj; }
  }
}

// ---------------------------------------------------------------------------
// k_alpha: p-order, 4 edges/thread vectorized (ushort4/float4), 4 independent
// aid/ajd table gathers in flight.
//   ex[p] = exp(leaky_relu(aid[dst]+ajd[src]+ewd[p]));  s[src] += ex
// ---------------------------------------------------------------------------
__global__ void k_alpha(const unsigned short* __restrict__ src_s,
                        const unsigned short* __restrict__ dst_s,
                        const float* __restrict__ aid, const float* __restrict__ ajd,
                        const float* __restrict__ ewd,
                        float* __restrict__ ex, float* __restrict__ s, int E) {
  int p4 = (blockIdx.x * 256 + threadIdx.x) * 4;
  if (p4 + 4 <= E) {
    ushort4 sv = *(const ushort4*)(src_s + p4);
    ushort4 dv = *(const ushort4*)(dst_s + p4);
    float4 ew = *(const float4*)(ewd + p4);
    float a0 = aid[dv.x] + ajd[sv.x] + ew.x;
    float a1 = aid[dv.y] + ajd[sv.y] + ew.y;
    float a2 = aid[dv.z] + ajd[sv.z] + ew.z;
    float a3 = aid[dv.w] + ajd[sv.w] + ew.w;
    a0 = (a0 > 0.f) ? a0 : a0 * NEG_SLOPE;
    a1 = (a1 > 0.f) ? a1 : a1 * NEG_SLOPE;
    a2 = (a2 > 0.f) ? a2 : a2 * NEG_SLOPE;
    a3 = (a3 > 0.f) ? a3 : a3 * NEG_SLOPE;
    float e0 = __expf(a0), e1 = __expf(a1), e2 = __expf(a2), e3 = __expf(a3);
    *(float4*)(ex + p4) = make_float4(e0, e1, e2, e3);
    atomicAdd(&s[sv.x], e0);
    atomicAdd(&s[sv.y], e1);
    atomicAdd(&s[sv.z], e2);
    atomicAdd(&s[sv.w], e3);
  } else if (p4 < E) {
    for (int p = p4; p < E; ++p) {
      int sn = src_s[p];
      float a = aid[dst_s[p]] + ajd[sn] + ewd[p];
      a = (a > 0.f) ? a : a * NEG_SLOPE;
      float ev = __expf(a);
      ex[p] = ev;
      atomicAdd(&s[sn], ev);
    }
  }
}

// ---------------------------------------------------------------------------
// k_agg: atomic-free aggregation over CSR-by-dst, half-wave edge split.
// R11 = verified R8 configuration (best measured: 551.6us total).
// 8-edge stride-2 halves (8 gathers in flight/wave), w recomputed in-loop
// (broadcast loads coalesce to one L2 txn/wave; R9's hoist was net-negative),
// readlane epilogue (no LDS traffic), __launch_bounds__(256,8) pins VGPR<=64
// -> 32 waves/CU for latency hiding.
// ---------------------------------------------------------------------------
__global__ __launch_bounds__(256, 8) void k_agg(const int* __restrict__ off,
                                             const unsigned short* __restrict__ src_s,
                                             const float* __restrict__ ex,
                                             const float* __restrict__ s,
                                             const bf16* __restrict__ x,
                                             const bf16* __restrict__ r_s,
                                             const float* __restrict__ rel_w,
                                             const float* __restrict__ rel_b,
                                             float* __restrict__ out, int N) {
  __shared__ float RT[32 * 64];  // RT[k][o] = rel_w[o][k]
  int t = threadIdx.x;
  for (int idx = t; idx < 2048; idx += 256) {
    int o = idx >> 5, kk = idx & 31;
    RT[kk * 64 + o] = rel_w[idx];
  }
  __syncthreads();
  int l = t & 63;
  int k = l & 31;        // lane within half; owns channels 2k, 2k+1
  int half = l >> 5;     // 0 or 1
  int wave = t >> 6;
  int nwaves = gridDim.x * 4;
  const unsigned short* xu = (const unsigned short*)x;
  const unsigned short* ru = (const unsigned short*)r_s;
  float2 rbl = *(const float2*)(rel_b + 2 * k);
  for (int n = blockIdx.x * 4 + wave; n < N; n += nwaves) {
    int p0 = off[n], p1 = off[n + 1];
    float ax0 = 0.f, ax1 = 0.f, aq = 0.f, ws = 0.f;
    int b = p0;
    for (; b + 8 <= p1; b += 8) {
      int q0 = b + half, q1 = q0 + 2, q2 = q0 + 4, q3 = q0 + 6;
      int s0 = src_s[q0], s1 = src_s[q1], s2 = src_s[q2], s3 = src_s[q3];
      float w0 = ex[q0] * __builtin_amdgcn_rcpf(s[s0] + 1e-16f);
      float w1 = ex[q1] * __builtin_amdgcn_rcpf(s[s1] + 1e-16f);
      float w2 = ex[q2] * __builtin_amdgcn_rcpf(s[s2] + 1e-16f);
      float w3 = ex[q3] * __builtin_amdgcn_rcpf(s[s3] + 1e-16f);
      // 8 independent 128B row gathers in flight per wave (4 per half)
      unsigned int xv0 = *(const unsigned int*)(xu + ((size_t)s0 << 6) + 2 * k);
      unsigned int xv1 = *(const unsigned int*)(xu + ((size_t)s1 << 6) + 2 * k);
      unsigned int xv2 = *(const unsigned int*)(xu + ((size_t)s2 << 6) + 2 * k);
      unsigned int xv3 = *(const unsigned int*)(xu + ((size_t)s3 << 6) + 2 * k);
      float rv0 = b2f(ru[(size_t)q0 * 32 + k]);
      float rv1 = b2f(ru[(size_t)q1 * 32 + k]);
      float rv2 = b2f(ru[(size_t)q2 * 32 + k]);
      float rv3 = b2f(ru[(size_t)q3 * 32 + k]);
      ax0 += w0 * bf_lo(xv0) + w1 * bf_lo(xv1) + w2 * bf_lo(xv2) + w3 * bf_lo(xv3);
      ax1 += w0 * bf_hi(xv0) + w1 * bf_hi(xv1) + w2 * bf_hi(xv2) + w3 * bf_hi(xv3);
      aq  += w0 * rv0 + w1 * rv1 + w2 * rv2 + w3 * rv3;
      ws  += w0 + w1 + w2 + w3;
    }
    for (; b + 2 <= p1; b += 2) {
      int q = b + half;
      int sn = src_s[q];
      float w = ex[q] * __builtin_amdgcn_rcpf(s[sn] + 1e-16f);
      unsigned int xv = *(const unsigned int*)(xu + ((size_t)sn << 6) + 2 * k);
      ax0 += w * bf_lo(xv);
      ax1 += w * bf_hi(xv);
      aq  += w * b2f(ru[(size_t)q * 32 + k]);
      ws  += w;
    }
    if (b < p1 && half == 0) {  // single leftover edge -> half 0
      int sn = src_s[b];
      float w = ex[b] * __builtin_amdgcn_rcpf(s[sn] + 1e-16f);
      unsigned int xv = *(const unsigned int*)(xu + ((size_t)sn << 6) + 2 * k);
      ax0 += w * bf_lo(xv);
      ax1 += w * bf_hi(xv);
      aq  += w * b2f(ru[(size_t)b * 32 + k]);
      ws  += w;
    }
    // merge the two halves (aq/ws/ax* identical in both halves afterwards)
    ax0 += __shfl_xor(ax0, 32, 64);
    ax1 += __shfl_xor(ax1, 32, 64);
    aq  += __shfl_xor(aq, 32, 64);
    ws  += __shfl_xor(ws, 32, 64);
    float a0 = ax0 + ws * rbl.x;
    float a1 = ax1 + ws * rbl.y;
    #pragma unroll
    for (int kk = 0; kk < 32; ++kk) {
      float qk = rdlane(aq, kk);  // constant-lane broadcast: no LDS traffic
      float2 rt = *(const float2*)(RT + kk * 64 + 2 * k);
      a0 += qk * rt.x;
      a1 += qk * rt.y;
    }
    if (half == 0) {
      *(float2*)(out + ((size_t)n << 6) + 2 * k) =
          make_float2(fmaxf(a0, 0.f), fmaxf(a1, 0.f));
    }
  }
}

// ---------------------------------------------------------------------------
extern "C" void kernel_launch(void* const* d_in, const int* in_sizes, int n_in,
                              void* d_out, int out_size, void* d_ws, size_t ws_size,
                              hipStream_t stream) {
  const float* feat   = (const float*)d_in[0];
  const int*   eidx   = (const int*)d_in[1];
  const float* r      = (const float*)d_in[2];
  const float* rel_w  = (const float*)d_in[3];
  const float* rel_b  = (const float*)d_in[4];
  const float* c1_lw  = (const float*)d_in[5];
  const float* c1_lb  = (const float*)d_in[6];
  const float* c1_aiw = (const float*)d_in[7];
  const float* c1_aib = (const float*)d_in[8];
  const float* c1_ajw = (const float*)d_in[9];
  const float* c1_ajb = (const float*)d_in[10];
  const float* c1_eww = (const float*)d_in[11];
  const float* c1_ewb = (const float*)d_in[12];
  const float* c2_lw  = (const float*)d_in[13];
  const float* c2_lb  = (const float*)d_in[14];
  const float* c2_aiw = (const float*)d_in[15];
  const float* c2_aib = (const float*)d_in[16];
  const float* c2_ajw = (const float*)d_in[17];
  const float* c2_ajb = (const float*)d_in[18];
  const float* c2_eww = (const float*)d_in[19];
  const float* c2_ewb = (const float*)d_in[20];
  float* out = (float*)d_out;

  const int N = in_sizes[0] / 64;
  const int E = in_sizes[1] / 2;
  const int* src = eidx;
  const int* dst = eidx + E;

  // ---- workspace carve (~91 MB) ----
  // s1, s2, deg are contiguous so one k_zero covers all three.
  float* wsf    = (float*)d_ws;
  float* consts = wsf;                          // 128
  float* ewd1_s = wsf + 128;                    // E (p-order)
  float* ewd2_s = ewd1_s + E;                   // E
  float* ex     = ewd2_s + E;                   // E
  float* s1     = ex + E;                       // N (zero region begin)
  float* s2     = s1 + N;                       // N
  int*   deg    = (int*)(s2 + N);               // N (zero region end)
  float* aid    = (float*)(deg + N);            // N
  float* ajd    = aid + N;                      // N
  float* h1     = ajd + N;                      // N*64 f32 (inter-layer, seq)
  bf16*  x      = (bf16*)(h1 + (size_t)N * 64); // N*64 bf16 (gathered table)
  int*   off    = (int*)(x + (size_t)N * 64);   // N+1
  int*   pos    = off + N + 1;                  // N
  int*   bsum   = pos + N;                      // 256
  int*   bsumx  = bsum + 256;                   // 256
  // 16B-align ed (u64 packed edge records)
  size_t ofs = (size_t)((char*)(bsumx + 256) - (char*)d_ws);
  ofs = (ofs + 15) & ~(size_t)15;
  unsigned long long* ed = (unsigned long long*)((char*)d_ws + ofs);  // E u64
  unsigned short* src_s = (unsigned short*)(ed + E);                  // E u16
  unsigned short* dst_s = src_s + E;                                  // E u16
  bf16* r_s = (bf16*)(dst_s + E);                                     // E*32 bf16

  const int blocksE4  = (E + 1023) / 1024;   // 4 edges/thread kernels
  const int blocksF   = 8 * blocksE4;        // k_fill: 8 partitions x chunks
  const int blocksP8  = (E + 63) / 64;       // k_perm: 8 groups x 8 rows/block
  const int blocksN   = (N + 255) / 256;
  const int blocksN3  = (3 * N + 255) / 256; // fused zero of s1,s2,deg
  const int gridP     = 2048;
  const int pw        = (N + 7) / 8;         // dst-partition width

  // ---- shared prep (both layers) ----
  k_zero<<<blocksN3, 256, 0, stream>>>((unsigned int*)s1, 3 * N);
  k_prep<<<1, 64, 0, stream>>>(rel_w, rel_b, c1_eww, c1_ewb, c2_eww, c2_ewb,
                               c1_aib, c1_ajb, c2_aib, c2_ajb, consts);
  k_deg<<<blocksE4, 256, 0, stream>>>(dst, deg, E);
  k_scan_sum<<<blocksN, 256, 0, stream>>>(deg, bsum, N);
  k_scan_bsum<<<1, 256, 0, stream>>>(bsum, bsumx, off, blocksN, N, E);
  k_scan_out<<<blocksN, 256, 0, stream>>>(deg, bsumx, off, pos, N);
  k_fill<<<blocksF, 256, 0, stream>>>(src, dst, pos, ed, E, pw, N);
  k_perm<<<blocksP8, 256, 0, stream>>>(ed, r, consts, ewd1_s, ewd2_s,
                                       src_s, dst_s, r_s, E);

  // ---- layer 1 ----
  k_x<<<gridP, 256, 0, stream>>>(feat, c1_lw, c1_lb, c1_aiw, c1_ajw, x, aid, ajd, N);
  k_alpha<<<blocksE4, 256, 0, stream>>>(src_s, dst_s, aid, ajd, ewd1_s, ex, s1, E);
  k_agg<<<gridP, 256, 0, stream>>>(off, src_s, ex, s1, x, r_s, rel_w, rel_b, h1, N);

  // ---- layer 2 ----
  k_x<<<gridP, 256, 0, stream>>>(h1, c2_lw, c2_lb, c2_aiw, c2_ajw, x, aid, ajd, N);
  k_alpha<<<blocksE4, 256, 0, stream>>>(src_s, dst_s, aid, ajd, ewd2_s, ex, s2, E);
  k_agg<<<gridP, 256, 0, stream>>>(off, src_s, ex, s2, x, r_s, rel_w, rel_b, out, N);
}